// Round 4
// baseline (512.976 us; speedup 1.0000x reference)
//
#include <hip/hip_runtime.h>
#include <cstddef>
#include <cstdint>

#define BZd   128
#define Td    32
#define Dd    768
#define DFFd  3072
#define Ed    8
#define NBEAM 256
#define ROWS_TOT 8192
#define OUT_ELEMS 6291456
#define MAXTILES 72
#define MAXT2    40

typedef unsigned short u16;
typedef __attribute__((ext_vector_type(4))) unsigned short ushort4v;
typedef __attribute__((ext_vector_type(8))) short frag_ab;
typedef __attribute__((ext_vector_type(4))) float floatx4;

__device__ __forceinline__ u16 f2bf(float f) {
  unsigned int u = __builtin_bit_cast(unsigned int, f);
  u += 0x7FFFu + ((u >> 16) & 1u);
  return (u16)(u >> 16);
}

__device__ __forceinline__ void async_copy16(u16* lds, const u16* g) {
  __builtin_amdgcn_global_load_lds(
      (const __attribute__((address_space(1))) void*)g,
      (__attribute__((address_space(3))) void*)lds, 16, 0, 0);
}

// fast gelu (tanh form via sigmoid): max abs err ~3e-4, << 0.14 threshold
__device__ __forceinline__ float gelu_fast(float x) {
  float z = 1.5957691216f * (x + 0.044715f * x * x * x);
  return x / (1.0f + __expf(-z));
}

// ---------------------------------------------------------------------------
// Routing (routing math byte-identical — near-tie softmax, don't perturb).
// NEW: after computing sel, all threads pre-write out[beam][tok][:] = b2[sel]
// (bias init for gemm2's split-K atomicAdd epilogue).
// ---------------------------------------------------------------------------
__global__ __launch_bounds__(256) void route_kernel(
    const float* __restrict__ x, const float* __restrict__ Wg,
    const float* __restrict__ b2, float* __restrict__ out,
    int* __restrict__ sel) {
  int b = blockIdx.x;
  int t = threadIdx.x;
  __shared__ float red[256][8];
  __shared__ int se2[2];
  float la[8];
#pragma unroll
  for (int e = 0; e < 8; e++) la[e] = 0.f;
  for (int d = t; d < Dd; d += 256) {
    const float* xp = x + (size_t)b * Td * Dd + d;
    float xa = 0.f;
#pragma unroll
    for (int tt = 0; tt < Td; tt++) xa += xp[(size_t)tt * Dd];
    xa *= (1.0f / 32.0f);
#pragma unroll
    for (int e = 0; e < 8; e++) la[e] += xa * Wg[d * 8 + e];
  }
#pragma unroll
  for (int e = 0; e < 8; e++) red[t][e] = la[e];
  __syncthreads();
  for (int s = 128; s > 0; s >>= 1) {
    if (t < s) {
#pragma unroll
      for (int e = 0; e < 8; e++) red[t][e] += red[t + s][e];
    }
    __syncthreads();
  }
  if (t == 0) {
    float lg[8];
#pragma unroll
    for (int e = 0; e < 8; e++) lg[e] = red[0][e];
    float mx = lg[0];
#pragma unroll
    for (int e = 1; e < 8; e++) mx = fmaxf(mx, lg[e]);
    float p[8];
    float sum = 0.f;
#pragma unroll
    for (int e = 0; e < 8; e++) { p[e] = __expf(lg[e] - mx); sum += p[e]; }
    float inv = 1.0f / sum;
#pragma unroll
    for (int e = 0; e < 8; e++) p[e] *= inv;
    int i0 = 0; float v0 = p[0];
#pragma unroll
    for (int e = 1; e < 8; e++) if (p[e] > v0) { v0 = p[e]; i0 = e; }
    int i1 = -1; float v1 = -1.0f;
#pragma unroll
    for (int e = 0; e < 8; e++) if (e != i0 && p[e] > v1) { v1 = p[e]; i1 = e; }
    float* bs = out + OUT_ELEMS;
    float* er = out + OUT_ELEMS + NBEAM;
    bs[2 * b] = v0; bs[2 * b + 1] = v1;
    er[2 * b] = (float)i0; er[2 * b + 1] = (float)i1;
    sel[2 * b] = i0; sel[2 * b + 1] = i1;
    se2[0] = i0; se2[1] = i1;
  }
  __syncthreads();
  // bias init: out[2b+bm][tok][d] = b2[se2[bm]][d]  (24576 f32 per beam)
#pragma unroll
  for (int bm = 0; bm < 2; bm++) {
    const float* brow = b2 + (size_t)se2[bm] * Dd;
    float* orow = out + (size_t)(2 * b + bm) * Td * Dd;
    for (int i = t; i < Td * Dd / 4; i += 256) {
      float4 v = *(const float4*)(brow + (i % (Dd / 4)) * 4);
      *(float4*)(orow + (size_t)i * 4) = v;
    }
  }
}

// ---------------------------------------------------------------------------
// Bucket: emits 256-row tiles (tiles2) used by both GEMMs
// ---------------------------------------------------------------------------
__global__ __launch_bounds__(256) void bucket_kernel(
    const int* __restrict__ sel, int* __restrict__ perm,
    int4* __restrict__ tiles, int4* __restrict__ tiles2) {
  __shared__ int ssel[NBEAM];
  __shared__ int scnt[8];
  __shared__ int soff[8];
  __shared__ int scur[8];
  __shared__ int sperm[NBEAM];
  int t = threadIdx.x;
  ssel[t] = sel[t];
  __syncthreads();
  if (t == 0) {
    for (int e = 0; e < 8; e++) scnt[e] = 0;
    for (int n = 0; n < NBEAM; n++) scnt[ssel[n]]++;
    int o = 0;
    for (int e = 0; e < 8; e++) { soff[e] = o; scur[e] = o; o += scnt[e]; }
    for (int n = 0; n < NBEAM; n++) { int e = ssel[n]; sperm[scur[e]++] = n; }
    int tt = 0;
    for (int e = 0; e < 8; e++) {
      int nr = scnt[e] * 32;
      int base = soff[e] * 32;
      for (int r0 = 0; r0 < nr; r0 += 128) {
        tiles[tt] = make_int4(e, base + r0, min(128, nr - r0), 0);
        tt++;
      }
    }
    for (; tt < MAXTILES; tt++) tiles[tt] = make_int4(-1, 0, 0, 0);
    int t2 = 0;
    for (int e = 0; e < 8; e++) {
      int nr = scnt[e] * 32;
      int base = soff[e] * 32;
      for (int r0 = 0; r0 < nr; r0 += 256) {
        tiles2[t2] = make_int4(e, base + r0, min(256, nr - r0), 0);
        t2++;
      }
    }
    for (; t2 < MAXT2; t2++) tiles2[t2] = make_int4(-1, 0, 0, 0);
  }
  __syncthreads();
  perm[t] = sperm[t];
}

// ---------------------------------------------------------------------------
// convert_x: fp32 -> bf16
// ---------------------------------------------------------------------------
__global__ __launch_bounds__(256) void convert_x_kernel(
    const float* __restrict__ x, u16* __restrict__ xbf) {
  size_t i = ((size_t)blockIdx.x * 256 + threadIdx.x) * 4;
  float4 v = *(const float4*)(x + i);
  ushort4v pv = {f2bf(v.x), f2bf(v.y), f2bf(v.z), f2bf(v.w)};
  *(ushort4v*)(xbf + i) = pv;
}

// ---------------------------------------------------------------------------
// Tiled transpose + fp32->bf16 (unchanged)
// ---------------------------------------------------------------------------
__global__ __launch_bounds__(256) void transpose_bf16_kernel(
    const float* __restrict__ in, u16* __restrict__ out, int row0, int col0,
    int ld_in, size_t estr_in, int ld_out, size_t estr_out) {
  __shared__ u16 tile[64][65];
  int e = blockIdx.z;
  int r0 = blockIdx.x * 64, c0 = blockIdx.y * 64;
  int t = threadIdx.x;
  int rr = t >> 4, cc4 = (t & 15) * 4;
  const float* ip = in + (size_t)e * estr_in + (size_t)(row0 + r0) * ld_in + col0 + c0;
#pragma unroll
  for (int i = 0; i < 4; i++) {
    int r = rr + 16 * i;
    float4 v = *(const float4*)(ip + (size_t)r * ld_in + cc4);
    tile[r][cc4 + 0] = f2bf(v.x);
    tile[r][cc4 + 1] = f2bf(v.y);
    tile[r][cc4 + 2] = f2bf(v.z);
    tile[r][cc4 + 3] = f2bf(v.w);
  }
  __syncthreads();
  int ccw = t >> 4, r4 = (t & 15) * 4;
  u16* op = out + (size_t)e * estr_out + (size_t)c0 * ld_out + r0;
#pragma unroll
  for (int i = 0; i < 4; i++) {
    int cc = ccw + 16 * i;
    ushort4v pv = {tile[r4 + 0][cc], tile[r4 + 1][cc], tile[r4 + 2][cc], tile[r4 + 3][cc]};
    *(ushort4v*)(op + (size_t)cc * ld_out + r4) = pv;
  }
}

// ---------------------------------------------------------------------------
// GEMM1: h = gelu(X @ W1T^T + b1). 256x256 tile, BK=64, 512 thr (8 waves,
// 2M x 4N, per-wave 128x64). Double-buffered 128 KB dynamic LDS. 4 sub-phases
// per K-tile, 2 staged loads/phase, counted vmcnt(2) at tile head, setprio
// around MFMA clusters. XOR chunk-swizzle (0 bank conflicts measured).
// ---------------------------------------------------------------------------
__global__ __launch_bounds__(512, 2) void gemm1_kernel(
    const u16* __restrict__ xbf, const u16* __restrict__ w1t,
    const float* __restrict__ b1, const int* __restrict__ perm,
    const int4* __restrict__ tiles2, u16* __restrict__ h, int f0, int FC) {
  int4 meta = tiles2[blockIdx.y];
  int e = meta.x;
  if (e < 0) return;
  int grow0 = meta.y, nrows = meta.z;
  int bx = blockIdx.x;

  extern __shared__ __align__(16) u16 smem[];
  u16* As = smem;            // 2 buffers x 16384 elems (32 KB each)
  u16* Bs = smem + 32768;    // 2 buffers x 16384 elems

  int t = threadIdx.x;
  int l = t & 63;
  int wid = t >> 6;
  int wr = wid >> 2;         // m-half (0..1): rows wr*128 ..
  int wc = wid & 3;          // n-quarter (0..3): cols wc*64 ..
  int lrow = l & 15, lquad = l >> 4;

  // staging: per thread 4 A-loads + 4 B-loads per K-tile (16B each)
  const u16* ag[4]; const u16* bg[4];
  int ldst[4];
#pragma unroll
  for (int j = 0; j < 4; j++) {
    int s = j * 512 + t;            // chunk id within 256x64 tile (8 chunks/row)
    int m = s >> 3;
    int koff = ((s & 7) ^ ((m >> 1) & 7)) * 8;   // inverse swizzle on SOURCE
    int gr = grow0 + m;
    int bidx = gr >> 5; bidx = bidx < NBEAM ? bidx : NBEAM - 1;
    int batch = perm[bidx] >> 1;
    ag[j] = xbf + ((size_t)batch * Td + (m & 31)) * Dd + koff;
    bg[j] = w1t + ((size_t)e * FC + bx * 256 + m) * Dd + koff;
    ldst[j] = j * 4096 + t * 8;     // linear LDS dest (elements)
  }

  // ds_read fragment bases; swizzle term constant across mi/wr (stride mult of 16)
  int swz = (lrow >> 1) & 7;
  int ca0 = (lquad ^ swz) * 8, ca1 = ((lquad + 4) ^ swz) * 8;
  int abase0 = (wr * 128 + lrow) * 64 + ca0;
  int abase1 = (wr * 128 + lrow) * 64 + ca1;
  int bbase0 = (wc * 64 + lrow) * 64 + ca0;
  int bbase1 = (wc * 64 + lrow) * 64 + ca1;

  floatx4 acc[8][4];
#pragma unroll
  for (int mi = 0; mi < 8; mi++)
#pragma unroll
    for (int ni = 0; ni < 4; ni++) acc[mi][ni] = (floatx4){0.f, 0.f, 0.f, 0.f};

  const int nk = Dd / 64;   // 12

  // prologue: tile 0 -> buffer 0
#pragma unroll
  for (int j = 0; j < 4; j++) { async_copy16(As + ldst[j], ag[j]); ag[j] += 64; }
#pragma unroll
  for (int j = 0; j < 4; j++) { async_copy16(Bs + ldst[j], bg[j]); bg[j] += 64; }

  for (int kt = 0; kt < nk; kt++) {
    const int b = kt & 1;
    const u16* Ab = As + b * 16384;
    const u16* Bb = Bs + b * 16384;
    const int pd = (b ^ 1) * 16384;
    const bool pre = (kt + 1 < nk);

    frag_ab af[4], bfr[4];

    // ---- phase 0: kk=0, m-half 0 ----
    if (pre) {
      async_copy16(As + pd + ldst[0], ag[0]); ag[0] += 64;
      async_copy16(As + pd + ldst[1], ag[1]); ag[1] += 64;
      asm volatile("s_waitcnt vmcnt(2)\n\ts_barrier" ::: "memory");
    } else {
      asm volatile("s_waitcnt vmcnt(0)\n\ts_barrier" ::: "memory");
    }
#pragma unroll
    for (int i = 0; i < 4; i++) bfr[i] = *(const frag_ab*)(Bb + bbase0 + i * 1024);
#pragma unroll
    for (int i = 0; i < 4; i++) af[i] = *(const frag_ab*)(Ab + abase0 + i * 1024);
    __builtin_amdgcn_s_setprio(1);
#pragma unroll
    for (int mi = 0; mi < 4; mi++)
#pragma unroll
      for (int ni = 0; ni < 4; ni++)
        acc[mi][ni] = __builtin_amdgcn_mfma_f32_16x16x32_bf16(bfr[ni], af[mi], acc[mi][ni], 0, 0, 0);
    __builtin_amdgcn_s_setprio(0);

    // ---- phase 1: kk=0, m-half 1 (reuse bfr) ----
    if (pre) {
      async_copy16(As + pd + ldst[2], ag[2]); ag[2] += 64;
      async_copy16(As + pd + ldst[3], ag[3]); ag[3] += 64;
    }
#pragma unroll
    for (int i = 0; i < 4; i++) af[i] = *(const frag_ab*)(Ab + abase0 + (i + 4) * 1024);
    __builtin_amdgcn_s_setprio(1);
#pragma unroll
    for (int mi = 0; mi < 4; mi++)
#pragma unroll
      for (int ni = 0; ni < 4; ni++)
        acc[mi + 4][ni] = __builtin_amdgcn_mfma_f32_16x16x32_bf16(bfr[ni], af[mi], acc[mi + 4][ni], 0, 0, 0);
    __builtin_amdgcn_s_setprio(0);

    // ---- phase 2: kk=1, m-half 0 ----
    if (pre) {
      async_copy16(Bs + pd + ldst[0], bg[0]); bg[0] += 64;
      async_copy16(Bs + pd + ldst[1], bg[1]); bg[1] += 64;
    }
#pragma unroll
    for (int i = 0; i < 4; i++) bfr[i] = *(const frag_ab*)(Bb + bbase1 + i * 1024);
#pragma unroll
    for (int i = 0; i < 4; i++) af[i] = *(const frag_ab*)(Ab + abase1 + i * 1024);
    __builtin_amdgcn_s_setprio(1);
#pragma unroll
    for (int mi = 0; mi < 4; mi++)
#pragma unroll
      for (int ni = 0; ni < 4; ni++)
        acc[mi][ni] = __builtin_amdgcn_mfma_f32_16x16x32_bf16(bfr[ni], af[mi], acc[mi][ni], 0, 0, 0);
    __builtin_amdgcn_s_setprio(0);

    // ---- phase 3: kk=1, m-half 1 ----
    if (pre) {
      async_copy16(Bs + pd + ldst[2], bg[2]); bg[2] += 64;
      async_copy16(Bs + pd + ldst[3], bg[3]); bg[3] += 64;
    }
#pragma unroll
    for (int i = 0; i < 4; i++) af[i] = *(const frag_ab*)(Ab + abase1 + (i + 4) * 1024);
    __builtin_amdgcn_s_setprio(1);
#pragma unroll
    for (int mi = 0; mi < 4; mi++)
#pragma unroll
      for (int ni = 0; ni < 4; ni++)
        acc[mi + 4][ni] = __builtin_amdgcn_mfma_f32_16x16x32_bf16(bfr[ni], af[mi], acc[mi + 4][ni], 0, 0, 0);
    __builtin_amdgcn_s_setprio(0);

    // tile boundary: everyone done reading buf b before it's restaged
    asm volatile("s_barrier" ::: "memory");
  }

  // Epilogue: D[row=f][col=token]; lane holds 4 consecutive f per acc frag.
#pragma unroll
  for (int mi = 0; mi < 8; mi++) {
    int row = wr * 128 + mi * 16 + lrow;          // token row within tile
    if (row < nrows) {
      u16* hp = h + (size_t)(grow0 + row) * FC + bx * 256 + wc * 64 + lquad * 4;
      const float* bp = b1 + (size_t)e * DFFd + f0 + bx * 256 + wc * 64 + lquad * 4;
#pragma unroll
      for (int ni = 0; ni < 4; ni++) {
        float4 bias = *(const float4*)(bp + ni * 16);
        ushort4v pv = {f2bf(gelu_fast(acc[mi][ni][0] + bias.x)),
                       f2bf(gelu_fast(acc[mi][ni][1] + bias.y)),
                       f2bf(gelu_fast(acc[mi][ni][2] + bias.z)),
                       f2bf(gelu_fast(acc[mi][ni][3] + bias.w))};
        *(ushort4v*)(hp + ni * 16) = pv;
      }
    }
  }
}

// ---------------------------------------------------------------------------
// GEMM2: out[beam][tok][d] += h @ W2T^T (bias pre-written by route_kernel).
// Same 256x256 8-wave pipelined structure, now split-K=2 via blockIdx.z
// (round-3 counters: only ~99 workgroups -> 60% of CUs idle; split-K doubles
// grid to ~204 single-round). Epilogue: f32 atomicAdd partials.
// ---------------------------------------------------------------------------
__global__ __launch_bounds__(512, 2) void gemm2_kernel(
    const u16* __restrict__ h, const u16* __restrict__ w2t,
    const int* __restrict__ perm, const int4* __restrict__ tiles2,
    float* __restrict__ out, int FC) {
  int4 meta = tiles2[blockIdx.y];
  int e = meta.x;
  if (e < 0) return;
  int grow0 = meta.y, nrows = meta.z;
  int bx = blockIdx.x;
  int kz = blockIdx.z;
  const int KC = FC >> 1;          // K-chunk per split (1536 when FC=3072)

  extern __shared__ __align__(16) u16 smem[];
  u16* As = smem;            // 2 x 16384 elems
  u16* Bs = smem + 32768;
  __shared__ int sbeam[8];

  int t = threadIdx.x;
  if (t < 8) {
    int idx = (grow0 >> 5) + t;
    sbeam[t] = perm[idx < NBEAM ? idx : NBEAM - 1];
  }
  __syncthreads();   // sbeam visible before raw-barrier loop

  int l = t & 63;
  int wid = t >> 6;
  int wr = wid >> 2;         // m-half
  int wc = wid & 3;          // n-quarter (d: wc*64 within 256-wide bx slab)
  int lrow = l & 15, lquad = l >> 4;

  const u16* ag[4]; const u16* bg[4];
  int ldst[4];
#pragma unroll
  for (int j = 0; j < 4; j++) {
    int s = j * 512 + t;
    int m = s >> 3;
    int koff = ((s & 7) ^ ((m >> 1) & 7)) * 8;
    int arow = grow0 + m;
    arow = arow < ROWS_TOT ? arow : ROWS_TOT - 1;
    ag[j] = h + (size_t)arow * FC + kz * KC + koff;
    bg[j] = w2t + ((size_t)e * Dd + bx * 256 + m) * FC + kz * KC + koff;
    ldst[j] = j * 4096 + t * 8;
  }

  int swz = (lrow >> 1) & 7;
  int ca0 = (lquad ^ swz) * 8, ca1 = ((lquad + 4) ^ swz) * 8;
  int abase0 = (wr * 128 + lrow) * 64 + ca0;
  int abase1 = (wr * 128 + lrow) * 64 + ca1;
  int bbase0 = (wc * 64 + lrow) * 64 + ca0;
  int bbase1 = (wc * 64 + lrow) * 64 + ca1;

  floatx4 acc[8][4];
#pragma unroll
  for (int mi = 0; mi < 8; mi++)
#pragma unroll
    for (int ni = 0; ni < 4; ni++) acc[mi][ni] = (floatx4){0.f, 0.f, 0.f, 0.f};

  const int nk = KC / 64;    // 24 when FC=3072

#pragma unroll
  for (int j = 0; j < 4; j++) { async_copy16(As + ldst[j], ag[j]); ag[j] += 64; }
#pragma unroll
  for (int j = 0; j < 4; j++) { async_copy16(Bs + ldst[j], bg[j]); bg[j] += 64; }

  for (int kt = 0; kt < nk; kt++) {
    const int b = kt & 1;
    const u16* Ab = As + b * 16384;
    const u16* Bb = Bs + b * 16384;
    const int pd = (b ^ 1) * 16384;
    const bool pre = (kt + 1 < nk);

    frag_ab af[4], bfr[4];

    // ---- phase 0 ----
    if (pre) {
      async_copy16(As + pd + ldst[0], ag[0]); ag[0] += 64;
      async_copy16(As + pd + ldst[1], ag[1]); ag[1] += 64;
      asm volatile("s_waitcnt vmcnt(2)\n\ts_barrier" ::: "memory");
    } else {
      asm volatile("s_waitcnt vmcnt(0)\n\ts_barrier" ::: "memory");
    }
#pragma unroll
    for (int i = 0; i < 4; i++) bfr[i] = *(const frag_ab*)(Bb + bbase0 + i * 1024);
#pragma unroll
    for (int i = 0; i < 4; i++) af[i] = *(const frag_ab*)(Ab + abase0 + i * 1024);
    __builtin_amdgcn_s_setprio(1);
#pragma unroll
    for (int mi = 0; mi < 4; mi++)
#pragma unroll
      for (int ni = 0; ni < 4; ni++)
        acc[mi][ni] = __builtin_amdgcn_mfma_f32_16x16x32_bf16(bfr[ni], af[mi], acc[mi][ni], 0, 0, 0);
    __builtin_amdgcn_s_setprio(0);

    // ---- phase 1 ----
    if (pre) {
      async_copy16(As + pd + ldst[2], ag[2]); ag[2] += 64;
      async_copy16(As + pd + ldst[3], ag[3]); ag[3] += 64;
    }
#pragma unroll
    for (int i = 0; i < 4; i++) af[i] = *(const frag_ab*)(Ab + abase0 + (i + 4) * 1024);
    __builtin_amdgcn_s_setprio(1);
#pragma unroll
    for (int mi = 0; mi < 4; mi++)
#pragma unroll
      for (int ni = 0; ni < 4; ni++)
        acc[mi + 4][ni] = __builtin_amdgcn_mfma_f32_16x16x32_bf16(bfr[ni], af[mi], acc[mi + 4][ni], 0, 0, 0);
    __builtin_amdgcn_s_setprio(0);

    // ---- phase 2 ----
    if (pre) {
      async_copy16(Bs + pd + ldst[0], bg[0]); bg[0] += 64;
      async_copy16(Bs + pd + ldst[1], bg[1]); bg[1] += 64;
    }
#pragma unroll
    for (int i = 0; i < 4; i++) bfr[i] = *(const frag_ab*)(Bb + bbase1 + i * 1024);
#pragma unroll
    for (int i = 0; i < 4; i++) af[i] = *(const frag_ab*)(Ab + abase1 + i * 1024);
    __builtin_amdgcn_s_setprio(1);
#pragma unroll
    for (int mi = 0; mi < 4; mi++)
#pragma unroll
      for (int ni = 0; ni < 4; ni++)
        acc[mi][ni] = __builtin_amdgcn_mfma_f32_16x16x32_bf16(bfr[ni], af[mi], acc[mi][ni], 0, 0, 0);
    __builtin_amdgcn_s_setprio(0);

    // ---- phase 3 ----
    if (pre) {
      async_copy16(Bs + pd + ldst[2], bg[2]); bg[2] += 64;
      async_copy16(Bs + pd + ldst[3], bg[3]); bg[3] += 64;
    }
#pragma unroll
    for (int i = 0; i < 4; i++) af[i] = *(const frag_ab*)(Ab + abase1 + (i + 4) * 1024);
    __builtin_amdgcn_s_setprio(1);
#pragma unroll
    for (int mi = 0; mi < 4; mi++)
#pragma unroll
      for (int ni = 0; ni < 4; ni++)
        acc[mi + 4][ni] = __builtin_amdgcn_mfma_f32_16x16x32_bf16(bfr[ni], af[mi], acc[mi + 4][ni], 0, 0, 0);
    __builtin_amdgcn_s_setprio(0);

    asm volatile("s_barrier" ::: "memory");
  }

  // Epilogue: atomicAdd f32 partials (bias pre-written by route_kernel).
#pragma unroll
  for (int mi = 0; mi < 8; mi++) {
    int row = wr * 128 + mi * 16 + lrow;          // token row within tile
    if (row < nrows) {
      int beam = sbeam[row >> 5];
      float* op = out + ((size_t)beam * Td + (row & 31)) * Dd + bx * 256 + wc * 64 + lquad * 4;
#pragma unroll
      for (int ni = 0; ni < 4; ni++) {
#pragma unroll
        for (int jj = 0; jj < 4; jj++)
          atomicAdd(op + ni * 16 + jj, acc[mi][ni][jj]);
      }
    }
  }
}

// ---------------------------------------------------------------------------
extern "C" void kernel_launch(void* const* d_in, const int* in_sizes, int n_in,
                              void* d_out, int out_size, void* d_ws, size_t ws_size,
                              hipStream_t stream) {
  const float* x  = (const float*)d_in[0];
  const float* Wg = (const float*)d_in[2];
  const float* W1 = (const float*)d_in[3];
  const float* b1 = (const float*)d_in[4];
  const float* W2 = (const float*)d_in[5];
  const float* b2 = (const float*)d_in[6];
  float* out = (float*)d_out;

  char* ws = (char*)d_ws;
  int*  sel    = (int*)ws;
  int*  perm   = sel + NBEAM;
  int4* tiles  = (int4*)(ws + 4096);
  int4* tiles2 = (int4*)(ws + 6144);

  const size_t xbf_off = 65536;
  const size_t xbf_bytes = (size_t)BZd * Td * Dd * 2;
  int FC = 768;
  if      (xbf_off + xbf_bytes + (size_t)40960 * 3072 <= ws_size) FC = 3072;
  else if (xbf_off + xbf_bytes + (size_t)40960 * 1536 <= ws_size) FC = 1536;
  int NC = DFFd / FC;

  u16* xbf = (u16*)(ws + xbf_off);
  u16* w1t = (u16*)(ws + xbf_off + xbf_bytes);
  u16* w2t = w1t + (size_t)Ed * FC * Dd;
  u16* h   = w2t + (size_t)Ed * Dd * FC;

  static bool attr_done = false;
  if (!attr_done) {
    hipFuncSetAttribute(reinterpret_cast<const void*>(gemm1_kernel),
                        hipFuncAttributeMaxDynamicSharedMemorySize, 131072);
    hipFuncSetAttribute(reinterpret_cast<const void*>(gemm2_kernel),
                        hipFuncAttributeMaxDynamicSharedMemorySize, 131072);
    attr_done = true;
  }

  route_kernel<<<BZd, 256, 0, stream>>>(x, Wg, b2, out, sel);
  bucket_kernel<<<1, 256, 0, stream>>>(sel, perm, tiles, tiles2);
  convert_x_kernel<<<(BZd * Td * Dd) / 1024, 256, 0, stream>>>(x, xbf);

  for (int c = 0; c < NC; c++) {
    transpose_bf16_kernel<<<dim3(Dd / 64, FC / 64, Ed), 256, 0, stream>>>(
        W1, w1t, 0, c * FC, DFFd, (size_t)Dd * DFFd, Dd, (size_t)FC * Dd);
    transpose_bf16_kernel<<<dim3(FC / 64, Dd / 64, Ed), 256, 0, stream>>>(
        W2, w2t, c * FC, 0, Dd, (size_t)DFFd * Dd, FC, (size_t)Dd * FC);
    gemm1_kernel<<<dim3(FC / 256, MAXT2), 512, 131072, stream>>>(
        xbf, w1t, b1, perm, tiles2, h, c * FC, FC);
    gemm2_kernel<<<dim3(Dd / 256, MAXT2, 2), 512, 131072, stream>>>(
        h, w2t, perm, tiles2, out, FC);
  }
}

// Round 5
// 371.718 us; speedup vs baseline: 1.3800x; 1.3800x over previous
//
#include <hip/hip_runtime.h>
#include <cstddef>
#include <cstdint>

#define BZd   128
#define Td    32
#define Dd    768
#define DFFd  3072
#define Ed    8
#define NBEAM 256
#define ROWS_TOT 8192
#define OUT_ELEMS 6291456
#define MAXTILES 72
#define MAXT2    40

typedef unsigned short u16;
typedef __attribute__((ext_vector_type(4))) unsigned short ushort4v;
typedef __attribute__((ext_vector_type(8))) short frag_ab;
typedef __attribute__((ext_vector_type(4))) float floatx4;

__device__ __forceinline__ u16 f2bf(float f) {
  unsigned int u = __builtin_bit_cast(unsigned int, f);
  u += 0x7FFFu + ((u >> 16) & 1u);
  return (u16)(u >> 16);
}

__device__ __forceinline__ void async_copy16(u16* lds, const u16* g) {
  __builtin_amdgcn_global_load_lds(
      (const __attribute__((address_space(1))) void*)g,
      (__attribute__((address_space(3))) void*)lds, 16, 0, 0);
}

// fast gelu (tanh form via sigmoid): max abs err ~3e-4, << 0.14 threshold
__device__ __forceinline__ float gelu_fast(float x) {
  float z = 1.5957691216f * (x + 0.044715f * x * x * x);
  return x / (1.0f + __expf(-z));
}

// ---------------------------------------------------------------------------
// Routing (byte-identical math — near-tie softmax, don't perturb)
// ---------------------------------------------------------------------------
__global__ __launch_bounds__(256) void route_kernel(
    const float* __restrict__ x, const float* __restrict__ Wg,
    float* __restrict__ out, int* __restrict__ sel) {
  int b = blockIdx.x;
  int t = threadIdx.x;
  __shared__ float red[256][8];
  float la[8];
#pragma unroll
  for (int e = 0; e < 8; e++) la[e] = 0.f;
  for (int d = t; d < Dd; d += 256) {
    const float* xp = x + (size_t)b * Td * Dd + d;
    float xa = 0.f;
#pragma unroll
    for (int tt = 0; tt < Td; tt++) xa += xp[(size_t)tt * Dd];
    xa *= (1.0f / 32.0f);
#pragma unroll
    for (int e = 0; e < 8; e++) la[e] += xa * Wg[d * 8 + e];
  }
#pragma unroll
  for (int e = 0; e < 8; e++) red[t][e] = la[e];
  __syncthreads();
  for (int s = 128; s > 0; s >>= 1) {
    if (t < s) {
#pragma unroll
      for (int e = 0; e < 8; e++) red[t][e] += red[t + s][e];
    }
    __syncthreads();
  }
  if (t == 0) {
    float lg[8];
#pragma unroll
    for (int e = 0; e < 8; e++) lg[e] = red[0][e];
    float mx = lg[0];
#pragma unroll
    for (int e = 1; e < 8; e++) mx = fmaxf(mx, lg[e]);
    float p[8];
    float sum = 0.f;
#pragma unroll
    for (int e = 0; e < 8; e++) { p[e] = __expf(lg[e] - mx); sum += p[e]; }
    float inv = 1.0f / sum;
#pragma unroll
    for (int e = 0; e < 8; e++) p[e] *= inv;
    int i0 = 0; float v0 = p[0];
#pragma unroll
    for (int e = 1; e < 8; e++) if (p[e] > v0) { v0 = p[e]; i0 = e; }
    int i1 = -1; float v1 = -1.0f;
#pragma unroll
    for (int e = 0; e < 8; e++) if (e != i0 && p[e] > v1) { v1 = p[e]; i1 = e; }
    float* bs = out + OUT_ELEMS;
    float* er = out + OUT_ELEMS + NBEAM;
    bs[2 * b] = v0; bs[2 * b + 1] = v1;
    er[2 * b] = (float)i0; er[2 * b + 1] = (float)i1;
    sel[2 * b] = i0; sel[2 * b + 1] = i1;
  }
}

// ---------------------------------------------------------------------------
// Bucket: emits 256-row tiles (tiles2) used by both GEMMs
// ---------------------------------------------------------------------------
__global__ __launch_bounds__(256) void bucket_kernel(
    const int* __restrict__ sel, int* __restrict__ perm,
    int4* __restrict__ tiles, int4* __restrict__ tiles2) {
  __shared__ int ssel[NBEAM];
  __shared__ int scnt[8];
  __shared__ int soff[8];
  __shared__ int scur[8];
  __shared__ int sperm[NBEAM];
  int t = threadIdx.x;
  ssel[t] = sel[t];
  __syncthreads();
  if (t == 0) {
    for (int e = 0; e < 8; e++) scnt[e] = 0;
    for (int n = 0; n < NBEAM; n++) scnt[ssel[n]]++;
    int o = 0;
    for (int e = 0; e < 8; e++) { soff[e] = o; scur[e] = o; o += scnt[e]; }
    for (int n = 0; n < NBEAM; n++) { int e = ssel[n]; sperm[scur[e]++] = n; }
    int tt = 0;
    for (int e = 0; e < 8; e++) {
      int nr = scnt[e] * 32;
      int base = soff[e] * 32;
      for (int r0 = 0; r0 < nr; r0 += 128) {
        tiles[tt] = make_int4(e, base + r0, min(128, nr - r0), 0);
        tt++;
      }
    }
    for (; tt < MAXTILES; tt++) tiles[tt] = make_int4(-1, 0, 0, 0);
    int t2 = 0;
    for (int e = 0; e < 8; e++) {
      int nr = scnt[e] * 32;
      int base = soff[e] * 32;
      for (int r0 = 0; r0 < nr; r0 += 256) {
        tiles2[t2] = make_int4(e, base + r0, min(256, nr - r0), 0);
        t2++;
      }
    }
    for (; t2 < MAXT2; t2++) tiles2[t2] = make_int4(-1, 0, 0, 0);
  }
  __syncthreads();
  perm[t] = sperm[t];
}

// ---------------------------------------------------------------------------
// convert_x: fp32 -> bf16
// ---------------------------------------------------------------------------
__global__ __launch_bounds__(256) void convert_x_kernel(
    const float* __restrict__ x, u16* __restrict__ xbf) {
  size_t i = ((size_t)blockIdx.x * 256 + threadIdx.x) * 4;
  float4 v = *(const float4*)(x + i);
  ushort4v pv = {f2bf(v.x), f2bf(v.y), f2bf(v.z), f2bf(v.w)};
  *(ushort4v*)(xbf + i) = pv;
}

// ---------------------------------------------------------------------------
// Tiled transpose + fp32->bf16 (unchanged)
// ---------------------------------------------------------------------------
__global__ __launch_bounds__(256) void transpose_bf16_kernel(
    const float* __restrict__ in, u16* __restrict__ out, int row0, int col0,
    int ld_in, size_t estr_in, int ld_out, size_t estr_out) {
  __shared__ u16 tile[64][65];
  int e = blockIdx.z;
  int r0 = blockIdx.x * 64, c0 = blockIdx.y * 64;
  int t = threadIdx.x;
  int rr = t >> 4, cc4 = (t & 15) * 4;
  const float* ip = in + (size_t)e * estr_in + (size_t)(row0 + r0) * ld_in + col0 + c0;
#pragma unroll
  for (int i = 0; i < 4; i++) {
    int r = rr + 16 * i;
    float4 v = *(const float4*)(ip + (size_t)r * ld_in + cc4);
    tile[r][cc4 + 0] = f2bf(v.x);
    tile[r][cc4 + 1] = f2bf(v.y);
    tile[r][cc4 + 2] = f2bf(v.z);
    tile[r][cc4 + 3] = f2bf(v.w);
  }
  __syncthreads();
  int ccw = t >> 4, r4 = (t & 15) * 4;
  u16* op = out + (size_t)e * estr_out + (size_t)c0 * ld_out + r0;
#pragma unroll
  for (int i = 0; i < 4; i++) {
    int cc = ccw + 16 * i;
    ushort4v pv = {tile[r4 + 0][cc], tile[r4 + 1][cc], tile[r4 + 2][cc], tile[r4 + 3][cc]};
    *(ushort4v*)(op + (size_t)cc * ld_out + r4) = pv;
  }
}

// ---------------------------------------------------------------------------
// GEMM1: h = gelu(X @ W1T^T + b1). 256x256 tile, BK=64, 512 thr (8 waves,
// 2M x 4N, per-wave 128x64). Double-buffered 128 KB dynamic LDS. 4 sub-phases
// per K-tile, 2 staged loads/phase, counted vmcnt(2) at tile head, setprio
// around MFMA clusters. XOR chunk-swizzle (0 bank conflicts measured).
// ---------------------------------------------------------------------------
__global__ __launch_bounds__(512, 2) void gemm1_kernel(
    const u16* __restrict__ xbf, const u16* __restrict__ w1t,
    const float* __restrict__ b1, const int* __restrict__ perm,
    const int4* __restrict__ tiles2, u16* __restrict__ h, int f0, int FC) {
  int4 meta = tiles2[blockIdx.y];
  int e = meta.x;
  if (e < 0) return;
  int grow0 = meta.y, nrows = meta.z;
  int bx = blockIdx.x;

  extern __shared__ __align__(16) u16 smem[];
  u16* As = smem;            // 2 buffers x 16384 elems (32 KB each)
  u16* Bs = smem + 32768;    // 2 buffers x 16384 elems

  int t = threadIdx.x;
  int l = t & 63;
  int wid = t >> 6;
  int wr = wid >> 2;         // m-half (0..1): rows wr*128 ..
  int wc = wid & 3;          // n-quarter (0..3): cols wc*64 ..
  int lrow = l & 15, lquad = l >> 4;

  // staging: per thread 4 A-loads + 4 B-loads per K-tile (16B each)
  const u16* ag[4]; const u16* bg[4];
  int ldst[4];
#pragma unroll
  for (int j = 0; j < 4; j++) {
    int s = j * 512 + t;            // chunk id within 256x64 tile (8 chunks/row)
    int m = s >> 3;
    int koff = ((s & 7) ^ ((m >> 1) & 7)) * 8;   // inverse swizzle on SOURCE
    int gr = grow0 + m;
    int bidx = gr >> 5; bidx = bidx < NBEAM ? bidx : NBEAM - 1;
    int batch = perm[bidx] >> 1;
    ag[j] = xbf + ((size_t)batch * Td + (m & 31)) * Dd + koff;
    bg[j] = w1t + ((size_t)e * FC + bx * 256 + m) * Dd + koff;
    ldst[j] = j * 4096 + t * 8;     // linear LDS dest (elements)
  }

  // ds_read fragment bases; swizzle term constant across mi/wr (stride mult of 16)
  int swz = (lrow >> 1) & 7;
  int ca0 = (lquad ^ swz) * 8, ca1 = ((lquad + 4) ^ swz) * 8;
  int abase0 = (wr * 128 + lrow) * 64 + ca0;
  int abase1 = (wr * 128 + lrow) * 64 + ca1;
  int bbase0 = (wc * 64 + lrow) * 64 + ca0;
  int bbase1 = (wc * 64 + lrow) * 64 + ca1;

  floatx4 acc[8][4];
#pragma unroll
  for (int mi = 0; mi < 8; mi++)
#pragma unroll
    for (int ni = 0; ni < 4; ni++) acc[mi][ni] = (floatx4){0.f, 0.f, 0.f, 0.f};

  const int nk = Dd / 64;   // 12

  // prologue: tile 0 -> buffer 0
#pragma unroll
  for (int j = 0; j < 4; j++) { async_copy16(As + ldst[j], ag[j]); ag[j] += 64; }
#pragma unroll
  for (int j = 0; j < 4; j++) { async_copy16(Bs + ldst[j], bg[j]); bg[j] += 64; }

  for (int kt = 0; kt < nk; kt++) {
    const int b = kt & 1;
    const u16* Ab = As + b * 16384;
    const u16* Bb = Bs + b * 16384;
    const int pd = (b ^ 1) * 16384;
    const bool pre = (kt + 1 < nk);

    frag_ab af[4], bfr[4];

    // ---- phase 0: kk=0, m-half 0 ----
    if (pre) {
      async_copy16(As + pd + ldst[0], ag[0]); ag[0] += 64;
      async_copy16(As + pd + ldst[1], ag[1]); ag[1] += 64;
      asm volatile("s_waitcnt vmcnt(2)\n\ts_barrier" ::: "memory");
    } else {
      asm volatile("s_waitcnt vmcnt(0)\n\ts_barrier" ::: "memory");
    }
#pragma unroll
    for (int i = 0; i < 4; i++) bfr[i] = *(const frag_ab*)(Bb + bbase0 + i * 1024);
#pragma unroll
    for (int i = 0; i < 4; i++) af[i] = *(const frag_ab*)(Ab + abase0 + i * 1024);
    __builtin_amdgcn_s_setprio(1);
#pragma unroll
    for (int mi = 0; mi < 4; mi++)
#pragma unroll
      for (int ni = 0; ni < 4; ni++)
        acc[mi][ni] = __builtin_amdgcn_mfma_f32_16x16x32_bf16(bfr[ni], af[mi], acc[mi][ni], 0, 0, 0);
    __builtin_amdgcn_s_setprio(0);

    // ---- phase 1: kk=0, m-half 1 (reuse bfr) ----
    if (pre) {
      async_copy16(As + pd + ldst[2], ag[2]); ag[2] += 64;
      async_copy16(As + pd + ldst[3], ag[3]); ag[3] += 64;
    }
#pragma unroll
    for (int i = 0; i < 4; i++) af[i] = *(const frag_ab*)(Ab + abase0 + (i + 4) * 1024);
    __builtin_amdgcn_s_setprio(1);
#pragma unroll
    for (int mi = 0; mi < 4; mi++)
#pragma unroll
      for (int ni = 0; ni < 4; ni++)
        acc[mi + 4][ni] = __builtin_amdgcn_mfma_f32_16x16x32_bf16(bfr[ni], af[mi], acc[mi + 4][ni], 0, 0, 0);
    __builtin_amdgcn_s_setprio(0);

    // ---- phase 2: kk=1, m-half 0 ----
    if (pre) {
      async_copy16(Bs + pd + ldst[0], bg[0]); bg[0] += 64;
      async_copy16(Bs + pd + ldst[1], bg[1]); bg[1] += 64;
    }
#pragma unroll
    for (int i = 0; i < 4; i++) bfr[i] = *(const frag_ab*)(Bb + bbase1 + i * 1024);
#pragma unroll
    for (int i = 0; i < 4; i++) af[i] = *(const frag_ab*)(Ab + abase1 + i * 1024);
    __builtin_amdgcn_s_setprio(1);
#pragma unroll
    for (int mi = 0; mi < 4; mi++)
#pragma unroll
      for (int ni = 0; ni < 4; ni++)
        acc[mi][ni] = __builtin_amdgcn_mfma_f32_16x16x32_bf16(bfr[ni], af[mi], acc[mi][ni], 0, 0, 0);
    __builtin_amdgcn_s_setprio(0);

    // ---- phase 3: kk=1, m-half 1 ----
    if (pre) {
      async_copy16(Bs + pd + ldst[2], bg[2]); bg[2] += 64;
      async_copy16(Bs + pd + ldst[3], bg[3]); bg[3] += 64;
    }
#pragma unroll
    for (int i = 0; i < 4; i++) af[i] = *(const frag_ab*)(Ab + abase1 + (i + 4) * 1024);
    __builtin_amdgcn_s_setprio(1);
#pragma unroll
    for (int mi = 0; mi < 4; mi++)
#pragma unroll
      for (int ni = 0; ni < 4; ni++)
        acc[mi + 4][ni] = __builtin_amdgcn_mfma_f32_16x16x32_bf16(bfr[ni], af[mi], acc[mi + 4][ni], 0, 0, 0);
    __builtin_amdgcn_s_setprio(0);

    // tile boundary: everyone done reading buf b before it's restaged
    asm volatile("s_barrier" ::: "memory");
  }

  // Epilogue: D[row=f][col=token]; lane holds 4 consecutive f per acc frag.
#pragma unroll
  for (int mi = 0; mi < 8; mi++) {
    int row = wr * 128 + mi * 16 + lrow;          // token row within tile
    if (row < nrows) {
      u16* hp = h + (size_t)(grow0 + row) * FC + bx * 256 + wc * 64 + lquad * 4;
      const float* bp = b1 + (size_t)e * DFFd + f0 + bx * 256 + wc * 64 + lquad * 4;
#pragma unroll
      for (int ni = 0; ni < 4; ni++) {
        float4 bias = *(const float4*)(bp + ni * 16);
        ushort4v pv = {f2bf(gelu_fast(acc[mi][ni][0] + bias.x)),
                       f2bf(gelu_fast(acc[mi][ni][1] + bias.y)),
                       f2bf(gelu_fast(acc[mi][ni][2] + bias.z)),
                       f2bf(gelu_fast(acc[mi][ni][3] + bias.w))};
        *(ushort4v*)(hp + ni * 16) = pv;
      }
    }
  }
}

// ---------------------------------------------------------------------------
// GEMM2: out[beam][tok][d] = h @ W2T^T + b2. 256x256 8-wave pipelined
// structure, split-K via blockIdx.z (round-3: 99 WGs starved 60% of CUs).
// NO atomics (round-4: atomicAdd epilogue = 8x write amplification, 215us).
// kz=0 writes out = acc + b2 (exclusive tiles, float4 stores); kz=1 writes
// raw partials to ws; reduce_kernel then does out += part.
// ---------------------------------------------------------------------------
__global__ __launch_bounds__(512, 2) void gemm2_kernel(
    const u16* __restrict__ h, const u16* __restrict__ w2t,
    const float* __restrict__ b2, const int* __restrict__ perm,
    const int4* __restrict__ tiles2, float* __restrict__ out,
    float* __restrict__ part, int FC, int first) {
  int4 meta = tiles2[blockIdx.y];
  int e = meta.x;
  if (e < 0) return;
  int grow0 = meta.y, nrows = meta.z;
  int bx = blockIdx.x;
  int kz = blockIdx.z;
  const int KC = FC / (int)gridDim.z;   // K-chunk per split

  extern __shared__ __align__(16) u16 smem[];
  u16* As = smem;            // 2 x 16384 elems
  u16* Bs = smem + 32768;
  __shared__ int sbeam[8];

  int t = threadIdx.x;
  if (t < 8) {
    int idx = (grow0 >> 5) + t;
    sbeam[t] = perm[idx < NBEAM ? idx : NBEAM - 1];
  }
  __syncthreads();   // sbeam visible before raw-barrier loop

  int l = t & 63;
  int wid = t >> 6;
  int wr = wid >> 2;         // m-half
  int wc = wid & 3;          // n-quarter (d: wc*64 within 256-wide bx slab)
  int lrow = l & 15, lquad = l >> 4;

  const u16* ag[4]; const u16* bg[4];
  int ldst[4];
#pragma unroll
  for (int j = 0; j < 4; j++) {
    int s = j * 512 + t;
    int m = s >> 3;
    int koff = ((s & 7) ^ ((m >> 1) & 7)) * 8;
    int arow = grow0 + m;
    arow = arow < ROWS_TOT ? arow : ROWS_TOT - 1;
    ag[j] = h + (size_t)arow * FC + kz * KC + koff;
    bg[j] = w2t + ((size_t)e * Dd + bx * 256 + m) * FC + kz * KC + koff;
    ldst[j] = j * 4096 + t * 8;
  }

  int swz = (lrow >> 1) & 7;
  int ca0 = (lquad ^ swz) * 8, ca1 = ((lquad + 4) ^ swz) * 8;
  int abase0 = (wr * 128 + lrow) * 64 + ca0;
  int abase1 = (wr * 128 + lrow) * 64 + ca1;
  int bbase0 = (wc * 64 + lrow) * 64 + ca0;
  int bbase1 = (wc * 64 + lrow) * 64 + ca1;

  floatx4 acc[8][4];
#pragma unroll
  for (int mi = 0; mi < 8; mi++)
#pragma unroll
    for (int ni = 0; ni < 4; ni++) acc[mi][ni] = (floatx4){0.f, 0.f, 0.f, 0.f};

  const int nk = KC / 64;

#pragma unroll
  for (int j = 0; j < 4; j++) { async_copy16(As + ldst[j], ag[j]); ag[j] += 64; }
#pragma unroll
  for (int j = 0; j < 4; j++) { async_copy16(Bs + ldst[j], bg[j]); bg[j] += 64; }

  for (int kt = 0; kt < nk; kt++) {
    const int b = kt & 1;
    const u16* Ab = As + b * 16384;
    const u16* Bb = Bs + b * 16384;
    const int pd = (b ^ 1) * 16384;
    const bool pre = (kt + 1 < nk);

    frag_ab af[4], bfr[4];

    // ---- phase 0 ----
    if (pre) {
      async_copy16(As + pd + ldst[0], ag[0]); ag[0] += 64;
      async_copy16(As + pd + ldst[1], ag[1]); ag[1] += 64;
      asm volatile("s_waitcnt vmcnt(2)\n\ts_barrier" ::: "memory");
    } else {
      asm volatile("s_waitcnt vmcnt(0)\n\ts_barrier" ::: "memory");
    }
#pragma unroll
    for (int i = 0; i < 4; i++) bfr[i] = *(const frag_ab*)(Bb + bbase0 + i * 1024);
#pragma unroll
    for (int i = 0; i < 4; i++) af[i] = *(const frag_ab*)(Ab + abase0 + i * 1024);
    __builtin_amdgcn_s_setprio(1);
#pragma unroll
    for (int mi = 0; mi < 4; mi++)
#pragma unroll
      for (int ni = 0; ni < 4; ni++)
        acc[mi][ni] = __builtin_amdgcn_mfma_f32_16x16x32_bf16(bfr[ni], af[mi], acc[mi][ni], 0, 0, 0);
    __builtin_amdgcn_s_setprio(0);

    // ---- phase 1 ----
    if (pre) {
      async_copy16(As + pd + ldst[2], ag[2]); ag[2] += 64;
      async_copy16(As + pd + ldst[3], ag[3]); ag[3] += 64;
    }
#pragma unroll
    for (int i = 0; i < 4; i++) af[i] = *(const frag_ab*)(Ab + abase0 + (i + 4) * 1024);
    __builtin_amdgcn_s_setprio(1);
#pragma unroll
    for (int mi = 0; mi < 4; mi++)
#pragma unroll
      for (int ni = 0; ni < 4; ni++)
        acc[mi + 4][ni] = __builtin_amdgcn_mfma_f32_16x16x32_bf16(bfr[ni], af[mi], acc[mi + 4][ni], 0, 0, 0);
    __builtin_amdgcn_s_setprio(0);

    // ---- phase 2 ----
    if (pre) {
      async_copy16(Bs + pd + ldst[0], bg[0]); bg[0] += 64;
      async_copy16(Bs + pd + ldst[1], bg[1]); bg[1] += 64;
    }
#pragma unroll
    for (int i = 0; i < 4; i++) bfr[i] = *(const frag_ab*)(Bb + bbase1 + i * 1024);
#pragma unroll
    for (int i = 0; i < 4; i++) af[i] = *(const frag_ab*)(Ab + abase1 + i * 1024);
    __builtin_amdgcn_s_setprio(1);
#pragma unroll
    for (int mi = 0; mi < 4; mi++)
#pragma unroll
      for (int ni = 0; ni < 4; ni++)
        acc[mi][ni] = __builtin_amdgcn_mfma_f32_16x16x32_bf16(bfr[ni], af[mi], acc[mi][ni], 0, 0, 0);
    __builtin_amdgcn_s_setprio(0);

    // ---- phase 3 ----
    if (pre) {
      async_copy16(Bs + pd + ldst[2], bg[2]); bg[2] += 64;
      async_copy16(Bs + pd + ldst[3], bg[3]); bg[3] += 64;
    }
#pragma unroll
    for (int i = 0; i < 4; i++) af[i] = *(const frag_ab*)(Ab + abase1 + (i + 4) * 1024);
    __builtin_amdgcn_s_setprio(1);
#pragma unroll
    for (int mi = 0; mi < 4; mi++)
#pragma unroll
      for (int ni = 0; ni < 4; ni++)
        acc[mi + 4][ni] = __builtin_amdgcn_mfma_f32_16x16x32_bf16(bfr[ni], af[mi], acc[mi + 4][ni], 0, 0, 0);
    __builtin_amdgcn_s_setprio(0);

    asm volatile("s_barrier" ::: "memory");
  }

  // Epilogue: float4 stores; kz0 -> out (+bias), kz1 -> part (raw partial).
#pragma unroll
  for (int mi = 0; mi < 8; mi++) {
    int row = wr * 128 + mi * 16 + lrow;          // token row within tile
    if (row < nrows) {
      int beam = sbeam[row >> 5];
      size_t base = ((size_t)beam * Td + (row & 31)) * Dd + bx * 256 + wc * 64 + lquad * 4;
      float* op = (kz == 0 ? out : part) + base;
      const float* bp = b2 + (size_t)e * Dd + bx * 256 + wc * 64 + lquad * 4;
#pragma unroll
      for (int ni = 0; ni < 4; ni++) {
        if (first) {
          float4 v = {acc[mi][ni][0], acc[mi][ni][1], acc[mi][ni][2], acc[mi][ni][3]};
          if (kz == 0) {
            float4 bias = *(const float4*)(bp + ni * 16);
            v.x += bias.x; v.y += bias.y; v.z += bias.z; v.w += bias.w;
          }
          *(float4*)(op + ni * 16) = v;
        } else {
          float4 o = *(float4*)(op + ni * 16);
          o.x += acc[mi][ni][0]; o.y += acc[mi][ni][1];
          o.z += acc[mi][ni][2]; o.w += acc[mi][ni][3];
          *(float4*)(op + ni * 16) = o;
        }
      }
    }
  }
}

// ---------------------------------------------------------------------------
// reduce: out += part (coalesced float4, 6144 blocks)
// ---------------------------------------------------------------------------
__global__ __launch_bounds__(256) void reduce_kernel(
    float* __restrict__ out, const float* __restrict__ part) {
  size_t i = ((size_t)blockIdx.x * 256 + threadIdx.x) * 4;
  float4 o = *(float4*)(out + i);
  float4 p = *(const float4*)(part + i);
  o.x += p.x; o.y += p.y; o.z += p.z; o.w += p.w;
  *(float4*)(out + i) = o;
}

// ---------------------------------------------------------------------------
extern "C" void kernel_launch(void* const* d_in, const int* in_sizes, int n_in,
                              void* d_out, int out_size, void* d_ws, size_t ws_size,
                              hipStream_t stream) {
  const float* x  = (const float*)d_in[0];
  const float* Wg = (const float*)d_in[2];
  const float* W1 = (const float*)d_in[3];
  const float* b1 = (const float*)d_in[4];
  const float* W2 = (const float*)d_in[5];
  const float* b2 = (const float*)d_in[6];
  float* out = (float*)d_out;

  char* ws = (char*)d_ws;
  int*  sel    = (int*)ws;
  int*  perm   = sel + NBEAM;
  int4* tiles  = (int4*)(ws + 4096);
  int4* tiles2 = (int4*)(ws + 6144);

  const size_t xbf_off = 65536;
  const size_t xbf_bytes = (size_t)BZd * Td * Dd * 2;
  int FC = 768;
  if      (xbf_off + xbf_bytes + (size_t)40960 * 3072 <= ws_size) FC = 3072;
  else if (xbf_off + xbf_bytes + (size_t)40960 * 1536 <= ws_size) FC = 1536;
  int NC = DFFd / FC;

  u16* xbf = (u16*)(ws + xbf_off);
  u16* w1t = (u16*)(ws + xbf_off + xbf_bytes);
  u16* w2t = w1t + (size_t)Ed * FC * Dd;
  u16* h   = w2t + (size_t)Ed * Dd * FC;

  // split-K partial buffer for gemm2 (layout identical to out's main region)
  const size_t part_off = xbf_off + xbf_bytes + (size_t)40960 * FC;
  const size_t part_bytes = (size_t)OUT_ELEMS * 4;
  int SPLIT = (part_off + part_bytes <= ws_size) ? 2 : 1;
  float* part = (float*)(ws + part_off);

  static bool attr_done = false;
  if (!attr_done) {
    hipFuncSetAttribute(reinterpret_cast<const void*>(gemm1_kernel),
                        hipFuncAttributeMaxDynamicSharedMemorySize, 131072);
    hipFuncSetAttribute(reinterpret_cast<const void*>(gemm2_kernel),
                        hipFuncAttributeMaxDynamicSharedMemorySize, 131072);
    attr_done = true;
  }

  route_kernel<<<BZd, 256, 0, stream>>>(x, Wg, out, sel);
  bucket_kernel<<<1, 256, 0, stream>>>(sel, perm, tiles, tiles2);
  convert_x_kernel<<<(BZd * Td * Dd) / 1024, 256, 0, stream>>>(x, xbf);

  for (int c = 0; c < NC; c++) {
    transpose_bf16_kernel<<<dim3(Dd / 64, FC / 64, Ed), 256, 0, stream>>>(
        W1, w1t, 0, c * FC, DFFd, (size_t)Dd * DFFd, Dd, (size_t)FC * Dd);
    transpose_bf16_kernel<<<dim3(FC / 64, Dd / 64, Ed), 256, 0, stream>>>(
        W2, w2t, c * FC, 0, Dd, (size_t)DFFd * Dd, FC, (size_t)Dd * FC);
    gemm1_kernel<<<dim3(FC / 256, MAXT2), 512, 131072, stream>>>(
        xbf, w1t, b1, perm, tiles2, h, c * FC, FC);
    gemm2_kernel<<<dim3(Dd / 256, MAXT2, SPLIT), 512, 131072, stream>>>(
        h, w2t, b2, perm, tiles2, out, part, FC, c == 0 ? 1 : 0);
  }
  if (SPLIT == 2)
    reduce_kernel<<<OUT_ELEMS / 1024, 256, 0, stream>>>(out, part);
}

// Round 6
// 364.059 us; speedup vs baseline: 1.4090x; 1.0210x over previous
//
#include <hip/hip_runtime.h>
#include <cstddef>
#include <cstdint>

#define BZd   128
#define Td    32
#define Dd    768
#define DFFd  3072
#define Ed    8
#define NBEAM 256
#define ROWS_TOT 8192
#define OUT_ELEMS 6291456
#define MAXTILES 72
#define MAXT2    40

typedef unsigned short u16;
typedef __attribute__((ext_vector_type(4))) unsigned short ushort4v;
typedef __attribute__((ext_vector_type(8))) short frag_ab;
typedef __attribute__((ext_vector_type(4))) float floatx4;

__device__ __forceinline__ u16 f2bf(float f) {
  unsigned int u = __builtin_bit_cast(unsigned int, f);
  u += 0x7FFFu + ((u >> 16) & 1u);
  return (u16)(u >> 16);
}

__device__ __forceinline__ void async_copy16(u16* lds, const u16* g) {
  __builtin_amdgcn_global_load_lds(
      (const __attribute__((address_space(1))) void*)g,
      (__attribute__((address_space(3))) void*)lds, 16, 0, 0);
}

// fast gelu (tanh form via sigmoid): max abs err ~3e-4, << 0.14 threshold
__device__ __forceinline__ float gelu_fast(float x) {
  float z = 1.5957691216f * (x + 0.044715f * x * x * x);
  return x / (1.0f + __expf(-z));
}

// ---------------------------------------------------------------------------
// Routing (routing math byte-identical — near-tie softmax, don't perturb).
// Fused: also converts this batch's x slab to bf16 (saves convert launch).
// ---------------------------------------------------------------------------
__global__ __launch_bounds__(256) void route_kernel(
    const float* __restrict__ x, const float* __restrict__ Wg,
    float* __restrict__ out, int* __restrict__ sel, u16* __restrict__ xbf) {
  int b = blockIdx.x;
  int t = threadIdx.x;
  __shared__ float red[256][8];
  float la[8];
#pragma unroll
  for (int e = 0; e < 8; e++) la[e] = 0.f;
  for (int d = t; d < Dd; d += 256) {
    const float* xp = x + (size_t)b * Td * Dd + d;
    float xa = 0.f;
#pragma unroll
    for (int tt = 0; tt < Td; tt++) xa += xp[(size_t)tt * Dd];
    xa *= (1.0f / 32.0f);
#pragma unroll
    for (int e = 0; e < 8; e++) la[e] += xa * Wg[d * 8 + e];
  }
#pragma unroll
  for (int e = 0; e < 8; e++) red[t][e] = la[e];
  __syncthreads();
  for (int s = 128; s > 0; s >>= 1) {
    if (t < s) {
#pragma unroll
      for (int e = 0; e < 8; e++) red[t][e] += red[t + s][e];
    }
    __syncthreads();
  }
  if (t == 0) {
    float lg[8];
#pragma unroll
    for (int e = 0; e < 8; e++) lg[e] = red[0][e];
    float mx = lg[0];
#pragma unroll
    for (int e = 1; e < 8; e++) mx = fmaxf(mx, lg[e]);
    float p[8];
    float sum = 0.f;
#pragma unroll
    for (int e = 0; e < 8; e++) { p[e] = __expf(lg[e] - mx); sum += p[e]; }
    float inv = 1.0f / sum;
#pragma unroll
    for (int e = 0; e < 8; e++) p[e] *= inv;
    int i0 = 0; float v0 = p[0];
#pragma unroll
    for (int e = 1; e < 8; e++) if (p[e] > v0) { v0 = p[e]; i0 = e; }
    int i1 = -1; float v1 = -1.0f;
#pragma unroll
    for (int e = 0; e < 8; e++) if (e != i0 && p[e] > v1) { v1 = p[e]; i1 = e; }
    float* bs = out + OUT_ELEMS;
    float* er = out + OUT_ELEMS + NBEAM;
    bs[2 * b] = v0; bs[2 * b + 1] = v1;
    er[2 * b] = (float)i0; er[2 * b + 1] = (float)i1;
    sel[2 * b] = i0; sel[2 * b + 1] = i1;
  }
  // fused fp32->bf16 convert of this batch's x slab (coalesced float4)
  const float* xs = x + (size_t)b * Td * Dd;
  u16* xd = xbf + (size_t)b * Td * Dd;
  for (int i = t; i < Td * Dd / 4; i += 256) {
    float4 v = *(const float4*)(xs + (size_t)i * 4);
    ushort4v pv = {f2bf(v.x), f2bf(v.y), f2bf(v.z), f2bf(v.w)};
    *(ushort4v*)(xd + (size_t)i * 4) = pv;
  }
}

// ---------------------------------------------------------------------------
// Bucket: emits 256-row tiles (tiles2) used by both GEMMs
// ---------------------------------------------------------------------------
__global__ __launch_bounds__(256) void bucket_kernel(
    const int* __restrict__ sel, int* __restrict__ perm,
    int4* __restrict__ tiles2) {
  __shared__ int ssel[NBEAM];
  __shared__ int scnt[8];
  __shared__ int soff[8];
  __shared__ int scur[8];
  __shared__ int sperm[NBEAM];
  int t = threadIdx.x;
  ssel[t] = sel[t];
  __syncthreads();
  if (t == 0) {
    for (int e = 0; e < 8; e++) scnt[e] = 0;
    for (int n = 0; n < NBEAM; n++) scnt[ssel[n]]++;
    int o = 0;
    for (int e = 0; e < 8; e++) { soff[e] = o; scur[e] = o; o += scnt[e]; }
    for (int n = 0; n < NBEAM; n++) { int e = ssel[n]; sperm[scur[e]++] = n; }
    int t2 = 0;
    for (int e = 0; e < 8; e++) {
      int nr = scnt[e] * 32;
      int base = soff[e] * 32;
      for (int r0 = 0; r0 < nr; r0 += 256) {
        tiles2[t2] = make_int4(e, base + r0, min(256, nr - r0), 0);
        t2++;
      }
    }
    for (; t2 < MAXT2; t2++) tiles2[t2] = make_int4(-1, 0, 0, 0);
  }
  __syncthreads();
  perm[t] = sperm[t];
}

// ---------------------------------------------------------------------------
// Merged transpose + fp32->bf16 for W1 and W2 in ONE launch.
// blockIdx.z: 0..7 -> W1 expert z; 8..15 -> W2 expert z-8.
// W1[e][768][DFF] -> w1t[e][FC][768] (chunk c); W2[e][DFF][768] -> w2t[e][768][FC].
// ---------------------------------------------------------------------------
__global__ __launch_bounds__(256) void transpose2_kernel(
    const float* __restrict__ W1, const float* __restrict__ W2,
    u16* __restrict__ w1t, u16* __restrict__ w2t, int c, int FC) {
  __shared__ u16 tile[64][65];
  int z = blockIdx.z;
  const float* in; u16* out;
  int e, r0, c0, row0, col0, ld_in, ld_out;
  size_t estr_in, estr_out;
  if (z < 8) {
    e = z; in = W1; out = w1t;
    row0 = 0; col0 = c * FC; ld_in = DFFd; estr_in = (size_t)Dd * DFFd;
    ld_out = Dd; estr_out = (size_t)FC * Dd;
    r0 = blockIdx.y * 64;          // rows: Dd/64 = 12
    c0 = blockIdx.x * 64;          // cols: FC/64
  } else {
    e = z - 8; in = W2; out = w2t;
    row0 = c * FC; col0 = 0; ld_in = Dd; estr_in = (size_t)DFFd * Dd;
    ld_out = FC; estr_out = (size_t)Dd * FC;
    r0 = blockIdx.x * 64;          // rows: FC/64
    c0 = blockIdx.y * 64;          // cols: Dd/64 = 12
  }
  int t = threadIdx.x;
  int rr = t >> 4, cc4 = (t & 15) * 4;
  const float* ip = in + (size_t)e * estr_in + (size_t)(row0 + r0) * ld_in + col0 + c0;
#pragma unroll
  for (int i = 0; i < 4; i++) {
    int r = rr + 16 * i;
    float4 v = *(const float4*)(ip + (size_t)r * ld_in + cc4);
    tile[r][cc4 + 0] = f2bf(v.x);
    tile[r][cc4 + 1] = f2bf(v.y);
    tile[r][cc4 + 2] = f2bf(v.z);
    tile[r][cc4 + 3] = f2bf(v.w);
  }
  __syncthreads();
  int ccw = t >> 4, r4 = (t & 15) * 4;
  u16* op = out + (size_t)e * estr_out + (size_t)c0 * ld_out + r0;
#pragma unroll
  for (int i = 0; i < 4; i++) {
    int cc = ccw + 16 * i;
    ushort4v pv = {tile[r4 + 0][cc], tile[r4 + 1][cc], tile[r4 + 2][cc], tile[r4 + 3][cc]};
    *(ushort4v*)(op + (size_t)cc * ld_out + r4) = pv;
  }
}

// ---------------------------------------------------------------------------
// GEMM1: h = gelu(X @ W1T^T + b1). 256x256 tile, BK=64, now 1024 thr /
// 16 waves (4M x 4N, per-wave 64x64): acc halves to 64 regs/lane so
// launch_bounds(1024,4) fits 4 waves/SIMD (round-5: 8-wave version was
// register-capped at 2 waves/SIMD -> read-burst/MFMA-burst serialization,
// MfmaUtil 24.5%). Same dbuf LDS, XOR swizzle, counted vmcnt, setprio.
// ---------------------------------------------------------------------------
__global__ __launch_bounds__(1024, 4) void gemm1_kernel(
    const u16* __restrict__ xbf, const u16* __restrict__ w1t,
    const float* __restrict__ b1, const int* __restrict__ perm,
    const int4* __restrict__ tiles2, u16* __restrict__ h, int f0, int FC) {
  int4 meta = tiles2[blockIdx.y];
  int e = meta.x;
  if (e < 0) return;
  int grow0 = meta.y, nrows = meta.z;
  int bx = blockIdx.x;

  extern __shared__ __align__(16) u16 smem[];
  u16* As = smem;            // 2 buffers x 16384 elems
  u16* Bs = smem + 32768;

  int t = threadIdx.x;
  int l = t & 63;
  int wid = t >> 6;          // 0..15
  int wr = wid >> 2;         // row quarter: rows wr*64 ..
  int wc = wid & 3;          // col quarter: cols wc*64 ..
  int lrow = l & 15, lquad = l >> 4;

  // staging: per thread 2 A + 2 B chunks (16B) per K-tile
  const u16* ag[2]; const u16* bg[2];
  int ldst[2];
#pragma unroll
  for (int j = 0; j < 2; j++) {
    int s = j * 1024 + t;           // chunk id (8 chunks/row, 256 rows)
    int m = s >> 3;
    int koff = ((s & 7) ^ ((m >> 1) & 7)) * 8;   // inverse swizzle on SOURCE
    int bidx = (grow0 + m) >> 5; bidx = bidx < NBEAM ? bidx : NBEAM - 1;
    int batch = perm[bidx] >> 1;
    ag[j] = xbf + ((size_t)batch * Td + (m & 31)) * Dd + koff;
    bg[j] = w1t + ((size_t)e * FC + bx * 256 + m) * Dd + koff;
    ldst[j] = s * 8;                // linear LDS dest (elements)
  }

  int swz = (lrow >> 1) & 7;
  int ca0 = (lquad ^ swz) * 8, ca1 = ((lquad + 4) ^ swz) * 8;
  int abase0 = (wr * 64 + lrow) * 64 + ca0;
  int abase1 = (wr * 64 + lrow) * 64 + ca1;
  int bbase0 = (wc * 64 + lrow) * 64 + ca0;
  int bbase1 = (wc * 64 + lrow) * 64 + ca1;

  floatx4 acc[4][4];
#pragma unroll
  for (int mi = 0; mi < 4; mi++)
#pragma unroll
    for (int ni = 0; ni < 4; ni++) acc[mi][ni] = (floatx4){0.f, 0.f, 0.f, 0.f};

  const int nk = Dd / 64;   // 12

  // prologue: tile 0 -> buffer 0
  async_copy16(As + ldst[0], ag[0]); ag[0] += 64;
  async_copy16(Bs + ldst[0], bg[0]); bg[0] += 64;
  async_copy16(As + ldst[1], ag[1]); ag[1] += 64;
  async_copy16(Bs + ldst[1], bg[1]); bg[1] += 64;

  for (int kt = 0; kt < nk; kt++) {
    const int b = kt & 1;
    const u16* Ab = As + b * 16384;
    const u16* Bb = Bs + b * 16384;
    const int pd = (b ^ 1) * 16384;
    const bool pre = (kt + 1 < nk);

    frag_ab af[2], bfr[4];

    // ---- phase 0: kk=0, mi 0-1 ----
    if (pre) {
      async_copy16(As + pd + ldst[0], ag[0]); ag[0] += 64;
      async_copy16(Bs + pd + ldst[0], bg[0]); bg[0] += 64;
      asm volatile("s_waitcnt vmcnt(2)\n\ts_barrier" ::: "memory");
    } else {
      asm volatile("s_waitcnt vmcnt(0)\n\ts_barrier" ::: "memory");
    }
#pragma unroll
    for (int i = 0; i < 4; i++) bfr[i] = *(const frag_ab*)(Bb + bbase0 + i * 1024);
#pragma unroll
    for (int i = 0; i < 2; i++) af[i] = *(const frag_ab*)(Ab + abase0 + i * 1024);
    __builtin_amdgcn_s_setprio(1);
#pragma unroll
    for (int mi = 0; mi < 2; mi++)
#pragma unroll
      for (int ni = 0; ni < 4; ni++)
        acc[mi][ni] = __builtin_amdgcn_mfma_f32_16x16x32_bf16(bfr[ni], af[mi], acc[mi][ni], 0, 0, 0);
    __builtin_amdgcn_s_setprio(0);

    // ---- phase 1: kk=0, mi 2-3 ----
    if (pre) {
      async_copy16(As + pd + ldst[1], ag[1]); ag[1] += 64;
      async_copy16(Bs + pd + ldst[1], bg[1]); bg[1] += 64;
    }
#pragma unroll
    for (int i = 0; i < 2; i++) af[i] = *(const frag_ab*)(Ab + abase0 + (i + 2) * 1024);
    __builtin_amdgcn_s_setprio(1);
#pragma unroll
    for (int mi = 0; mi < 2; mi++)
#pragma unroll
      for (int ni = 0; ni < 4; ni++)
        acc[mi + 2][ni] = __builtin_amdgcn_mfma_f32_16x16x32_bf16(bfr[ni], af[mi], acc[mi + 2][ni], 0, 0, 0);
    __builtin_amdgcn_s_setprio(0);

    // ---- phase 2: kk=1, mi 0-1 ----
#pragma unroll
    for (int i = 0; i < 4; i++) bfr[i] = *(const frag_ab*)(Bb + bbase1 + i * 1024);
#pragma unroll
    for (int i = 0; i < 2; i++) af[i] = *(const frag_ab*)(Ab + abase1 + i * 1024);
    __builtin_amdgcn_s_setprio(1);
#pragma unroll
    for (int mi = 0; mi < 2; mi++)
#pragma unroll
      for (int ni = 0; ni < 4; ni++)
        acc[mi][ni] = __builtin_amdgcn_mfma_f32_16x16x32_bf16(bfr[ni], af[mi], acc[mi][ni], 0, 0, 0);
    __builtin_amdgcn_s_setprio(0);

    // ---- phase 3: kk=1, mi 2-3 ----
#pragma unroll
    for (int i = 0; i < 2; i++) af[i] = *(const frag_ab*)(Ab + abase1 + (i + 2) * 1024);
    __builtin_amdgcn_s_setprio(1);
#pragma unroll
    for (int mi = 0; mi < 2; mi++)
#pragma unroll
      for (int ni = 0; ni < 4; ni++)
        acc[mi + 2][ni] = __builtin_amdgcn_mfma_f32_16x16x32_bf16(bfr[ni], af[mi], acc[mi + 2][ni], 0, 0, 0);
    __builtin_amdgcn_s_setprio(0);

    // tile boundary: everyone done reading buf b before it's restaged
    asm volatile("s_barrier" ::: "memory");
  }

  // Epilogue: D[row=f][col=token]; lane holds 4 consecutive f per acc frag.
#pragma unroll
  for (int mi = 0; mi < 4; mi++) {
    int row = wr * 64 + mi * 16 + lrow;           // token row within tile
    if (row < nrows) {
      u16* hp = h + (size_t)(grow0 + row) * FC + bx * 256 + wc * 64 + lquad * 4;
      const float* bp = b1 + (size_t)e * DFFd + f0 + bx * 256 + wc * 64 + lquad * 4;
#pragma unroll
      for (int ni = 0; ni < 4; ni++) {
        float4 bias = *(const float4*)(bp + ni * 16);
        ushort4v pv = {f2bf(gelu_fast(acc[mi][ni][0] + bias.x)),
                       f2bf(gelu_fast(acc[mi][ni][1] + bias.y)),
                       f2bf(gelu_fast(acc[mi][ni][2] + bias.z)),
                       f2bf(gelu_fast(acc[mi][ni][3] + bias.w))};
        *(ushort4v*)(hp + ni * 16) = pv;
      }
    }
  }
}

// ---------------------------------------------------------------------------
// GEMM2: out = h @ W2T^T + b2. Same 16-wave 256x256 structure; split-K via
// blockIdx.z (kz=0 -> out with bias, kz=1 -> partials to ws; reduce adds).
// ---------------------------------------------------------------------------
__global__ __launch_bounds__(1024, 4) void gemm2_kernel(
    const u16* __restrict__ h, const u16* __restrict__ w2t,
    const float* __restrict__ b2, const int* __restrict__ perm,
    const int4* __restrict__ tiles2, float* __restrict__ out,
    float* __restrict__ part, int FC, int first) {
  int4 meta = tiles2[blockIdx.y];
  int e = meta.x;
  if (e < 0) return;
  int grow0 = meta.y, nrows = meta.z;
  int bx = blockIdx.x;
  int kz = blockIdx.z;
  const int KC = FC / (int)gridDim.z;

  extern __shared__ __align__(16) u16 smem[];
  u16* As = smem;
  u16* Bs = smem + 32768;
  __shared__ int sbeam[8];

  int t = threadIdx.x;
  if (t < 8) {
    int idx = (grow0 >> 5) + t;
    sbeam[t] = perm[idx < NBEAM ? idx : NBEAM - 1];
  }
  __syncthreads();   // sbeam visible before raw-barrier loop

  int l = t & 63;
  int wid = t >> 6;
  int wr = wid >> 2;
  int wc = wid & 3;
  int lrow = l & 15, lquad = l >> 4;

  const u16* ag[2]; const u16* bg[2];
  int ldst[2];
#pragma unroll
  for (int j = 0; j < 2; j++) {
    int s = j * 1024 + t;
    int m = s >> 3;
    int koff = ((s & 7) ^ ((m >> 1) & 7)) * 8;
    int arow = grow0 + m;
    arow = arow < ROWS_TOT ? arow : ROWS_TOT - 1;
    ag[j] = h + (size_t)arow * FC + kz * KC + koff;
    bg[j] = w2t + ((size_t)e * Dd + bx * 256 + m) * FC + kz * KC + koff;
    ldst[j] = s * 8;
  }

  int swz = (lrow >> 1) & 7;
  int ca0 = (lquad ^ swz) * 8, ca1 = ((lquad + 4) ^ swz) * 8;
  int abase0 = (wr * 64 + lrow) * 64 + ca0;
  int abase1 = (wr * 64 + lrow) * 64 + ca1;
  int bbase0 = (wc * 64 + lrow) * 64 + ca0;
  int bbase1 = (wc * 64 + lrow) * 64 + ca1;

  floatx4 acc[4][4];
#pragma unroll
  for (int mi = 0; mi < 4; mi++)
#pragma unroll
    for (int ni = 0; ni < 4; ni++) acc[mi][ni] = (floatx4){0.f, 0.f, 0.f, 0.f};

  const int nk = KC / 64;

  async_copy16(As + ldst[0], ag[0]); ag[0] += 64;
  async_copy16(Bs + ldst[0], bg[0]); bg[0] += 64;
  async_copy16(As + ldst[1], ag[1]); ag[1] += 64;
  async_copy16(Bs + ldst[1], bg[1]); bg[1] += 64;

  for (int kt = 0; kt < nk; kt++) {
    const int b = kt & 1;
    const u16* Ab = As + b * 16384;
    const u16* Bb = Bs + b * 16384;
    const int pd = (b ^ 1) * 16384;
    const bool pre = (kt + 1 < nk);

    frag_ab af[2], bfr[4];

    // ---- phase 0: kk=0, mi 0-1 ----
    if (pre) {
      async_copy16(As + pd + ldst[0], ag[0]); ag[0] += 64;
      async_copy16(Bs + pd + ldst[0], bg[0]); bg[0] += 64;
      asm volatile("s_waitcnt vmcnt(2)\n\ts_barrier" ::: "memory");
    } else {
      asm volatile("s_waitcnt vmcnt(0)\n\ts_barrier" ::: "memory");
    }
#pragma unroll
    for (int i = 0; i < 4; i++) bfr[i] = *(const frag_ab*)(Bb + bbase0 + i * 1024);
#pragma unroll
    for (int i = 0; i < 2; i++) af[i] = *(const frag_ab*)(Ab + abase0 + i * 1024);
    __builtin_amdgcn_s_setprio(1);
#pragma unroll
    for (int mi = 0; mi < 2; mi++)
#pragma unroll
      for (int ni = 0; ni < 4; ni++)
        acc[mi][ni] = __builtin_amdgcn_mfma_f32_16x16x32_bf16(bfr[ni], af[mi], acc[mi][ni], 0, 0, 0);
    __builtin_amdgcn_s_setprio(0);

    // ---- phase 1: kk=0, mi 2-3 ----
    if (pre) {
      async_copy16(As + pd + ldst[1], ag[1]); ag[1] += 64;
      async_copy16(Bs + pd + ldst[1], bg[1]); bg[1] += 64;
    }
#pragma unroll
    for (int i = 0; i < 2; i++) af[i] = *(const frag_ab*)(Ab + abase0 + (i + 2) * 1024);
    __builtin_amdgcn_s_setprio(1);
#pragma unroll
    for (int mi = 0; mi < 2; mi++)
#pragma unroll
      for (int ni = 0; ni < 4; ni++)
        acc[mi + 2][ni] = __builtin_amdgcn_mfma_f32_16x16x32_bf16(bfr[ni], af[mi], acc[mi + 2][ni], 0, 0, 0);
    __builtin_amdgcn_s_setprio(0);

    // ---- phase 2: kk=1, mi 0-1 ----
#pragma unroll
    for (int i = 0; i < 4; i++) bfr[i] = *(const frag_ab*)(Bb + bbase1 + i * 1024);
#pragma unroll
    for (int i = 0; i < 2; i++) af[i] = *(const frag_ab*)(Ab + abase1 + i * 1024);
    __builtin_amdgcn_s_setprio(1);
#pragma unroll
    for (int mi = 0; mi < 2; mi++)
#pragma unroll
      for (int ni = 0; ni < 4; ni++)
        acc[mi][ni] = __builtin_amdgcn_mfma_f32_16x16x32_bf16(bfr[ni], af[mi], acc[mi][ni], 0, 0, 0);
    __builtin_amdgcn_s_setprio(0);

    // ---- phase 3: kk=1, mi 2-3 ----
#pragma unroll
    for (int i = 0; i < 2; i++) af[i] = *(const frag_ab*)(Ab + abase1 + (i + 2) * 1024);
    __builtin_amdgcn_s_setprio(1);
#pragma unroll
    for (int mi = 0; mi < 2; mi++)
#pragma unroll
      for (int ni = 0; ni < 4; ni++)
        acc[mi + 2][ni] = __builtin_amdgcn_mfma_f32_16x16x32_bf16(bfr[ni], af[mi], acc[mi + 2][ni], 0, 0, 0);
    __builtin_amdgcn_s_setprio(0);

    asm volatile("s_barrier" ::: "memory");
  }

  // Epilogue: float4 stores; kz0 -> out (+bias), kz1 -> part (raw partial).
#pragma unroll
  for (int mi = 0; mi < 4; mi++) {
    int row = wr * 64 + mi * 16 + lrow;           // token row within tile
    if (row < nrows) {
      int beam = sbeam[row >> 5];
      size_t base = ((size_t)beam * Td + (row & 31)) * Dd + bx * 256 + wc * 64 + lquad * 4;
      float* op = (kz == 0 ? out : part) + base;
      const float* bp = b2 + (size_t)e * Dd + bx * 256 + wc * 64 + lquad * 4;
#pragma unroll
      for (int ni = 0; ni < 4; ni++) {
        if (first) {
          float4 v = {acc[mi][ni][0], acc[mi][ni][1], acc[mi][ni][2], acc[mi][ni][3]};
          if (kz == 0) {
            float4 bias = *(const float4*)(bp + ni * 16);
            v.x += bias.x; v.y += bias.y; v.z += bias.z; v.w += bias.w;
          }
          *(float4*)(op + ni * 16) = v;
        } else {
          float4 o = *(float4*)(op + ni * 16);
          o.x += acc[mi][ni][0]; o.y += acc[mi][ni][1];
          o.z += acc[mi][ni][2]; o.w += acc[mi][ni][3];
          *(float4*)(op + ni * 16) = o;
        }
      }
    }
  }
}

// ---------------------------------------------------------------------------
// reduce: out += part (coalesced float4)
// ---------------------------------------------------------------------------
__global__ __launch_bounds__(256) void reduce_kernel(
    float* __restrict__ out, const float* __restrict__ part) {
  size_t i = ((size_t)blockIdx.x * 256 + threadIdx.x) * 4;
  float4 o = *(float4*)(out + i);
  float4 p = *(const float4*)(part + i);
  o.x += p.x; o.y += p.y; o.z += p.z; o.w += p.w;
  *(float4*)(out + i) = o;
}

// ---------------------------------------------------------------------------
extern "C" void kernel_launch(void* const* d_in, const int* in_sizes, int n_in,
                              void* d_out, int out_size, void* d_ws, size_t ws_size,
                              hipStream_t stream) {
  const float* x  = (const float*)d_in[0];
  const float* Wg = (const float*)d_in[2];
  const float* W1 = (const float*)d_in[3];
  const float* b1 = (const float*)d_in[4];
  const float* W2 = (const float*)d_in[5];
  const float* b2 = (const float*)d_in[6];
  float* out = (float*)d_out;

  char* ws = (char*)d_ws;
  int*  sel    = (int*)ws;
  int*  perm   = sel + NBEAM;
  int4* tiles2 = (int4*)(ws + 6144);

  const size_t xbf_off = 65536;
  const size_t xbf_bytes = (size_t)BZd * Td * Dd * 2;
  int FC = 768;
  if      (xbf_off + xbf_bytes + (size_t)40960 * 3072 <= ws_size) FC = 3072;
  else if (xbf_off + xbf_bytes + (size_t)40960 * 1536 <= ws_size) FC = 1536;
  int NC = DFFd / FC;

  u16* xbf = (u16*)(ws + xbf_off);
  u16* w1t = (u16*)(ws + xbf_off + xbf_bytes);
  u16* w2t = w1t + (size_t)Ed * FC * Dd;
  u16* h   = w2t + (size_t)Ed * Dd * FC;

  // split-K partial buffer for gemm2 (layout identical to out's main region)
  const size_t part_off = xbf_off + xbf_bytes + (size_t)40960 * FC;
  const size_t part_bytes = (size_t)OUT_ELEMS * 4;
  int SPLIT = (part_off + part_bytes <= ws_size) ? 2 : 1;
  float* part = (float*)(ws + part_off);

  static bool attr_done = false;
  if (!attr_done) {
    hipFuncSetAttribute(reinterpret_cast<const void*>(gemm1_kernel),
                        hipFuncAttributeMaxDynamicSharedMemorySize, 131072);
    hipFuncSetAttribute(reinterpret_cast<const void*>(gemm2_kernel),
                        hipFuncAttributeMaxDynamicSharedMemorySize, 131072);
    attr_done = true;
  }

  route_kernel<<<BZd, 256, 0, stream>>>(x, Wg, out, sel, xbf);
  bucket_kernel<<<1, 256, 0, stream>>>(sel, perm, tiles2);

  for (int c = 0; c < NC; c++) {
    transpose2_kernel<<<dim3(FC / 64, Dd / 64, 2 * Ed), 256, 0, stream>>>(
        W1, W2, w1t, w2t, c, FC);
    gemm1_kernel<<<dim3(FC / 256, MAXT2), 1024, 131072, stream>>>(
        xbf, w1t, b1, perm, tiles2, h, c * FC, FC);
    gemm2_kernel<<<dim3(Dd / 256, MAXT2, SPLIT), 1024, 131072, stream>>>(
        h, w2t, b2, perm, tiles2, out, part, FC, c == 0 ? 1 : 0);
  }
  if (SPLIT == 2)
    reduce_kernel<<<OUT_ELEMS / 1024, 256, 0, stream>>>(out, part);
}